// Round 2
// baseline (20382.281 us; speedup 1.0000x reference)
//
#include <hip/hip_runtime.h>

// mRNN: h_{t+1} = h + 0.1*(-h + relu(h) @ W_eff^T + tonic + ext) + 0.01*noise
// out[b,t] = sum_alm relu(h[500:600]) * out_w
//
// Strategy: 1 WG per batch (128 WGs, 512 thr = 8 waves). W_eff is block-sparse
// (11 region blocks, ~97k nz). Prep kernel packs it as f16 pairs, quad-padded,
// [block][half][q][lane] (lane = target row). Main kernel loads ALL W into
// per-lane REGISTERS once (max 36 uint4 = 144 VGPR/lane), then iterates 1000
// steps: r=relu(h) kept in double-buffered f16 LDS; r quads read as uniform
// ds_read_b128 broadcasts; MACs via fma_mix-friendly (float)f16*(float)f16.
//
// R1 fix: __launch_bounds__(512,2) made the backend cap VGPRs at 128 -> the
// 144-VGPR weight arrays spilled to scratch and were re-read every step
// (WRITE_SIZE 39MB of spill stores, FETCH 2.5GB, 20.3ms latency-bound).
// Use plain __launch_bounds__(512) + amdgpu_waves_per_eu(2,2) -> 256-VGPR
// budget, weights stay register-resident.

typedef _Float16 f16;
typedef _Float16 h2v __attribute__((ext_vector_type(2)));

__device__ __forceinline__ unsigned pack_f16x2(float a, float b){
  union { f16 h[2]; unsigned u; } cv;
  cv.h[0] = (f16)a; cv.h[1] = (f16)b;
  return cv.u;
}

// 2 MACs: acc += w.lo*r.lo + w.hi*r.hi  (f16 inputs, f32 accumulate)
__device__ __forceinline__ void mac2(unsigned w, unsigned r, float& acc){
  union { unsigned u; h2v v; } cw, cr;
  cw.u = w; cr.u = r;
  acc += (float)cw.v.x * (float)cr.v.x;
  acc += (float)cw.v.y * (float)cr.v.y;
}

// ---------------- block tables ----------------
// 11 blocks: (qoff in uint4 units, Q quads/row, tgt_base, src extent, r-pair base)
// quad = 4 f16 pairs = 8 sources, aligned so r reads are 16B-aligned.
namespace tb {
constexpr int qoffs[12] = {0,1300,2600,3600,4900,5600,6900,7600,8900,10200,11500,12800};
constexpr int Qs [11] = {13,13,10,13, 7,13, 7,13,13,13,13};
constexpr int tgt[11] = {0,0,0,0,100,200,300,300,400,500,500};
constexpr int slo[11] = {0,400,500,600, 50,100,  0,200,300,400,500};
constexpr int shi[11] = {100,500,570,700,100,200, 50,300,400,500,600};
constexpr int rpb[11] = {0,200,248,300, 24, 48,  0,100,148,200,248};
}

// ---------------- prep: pack W_eff ----------------
__device__ __forceinline__ float wval(const float* __restrict__ Wrec,
    const float* __restrict__ Wm, const float* __restrict__ Ws,
    const float* __restrict__ Wf, int i, int j, int lo, int hi){
  if (j < lo || j >= hi) return 0.f;
  int idx = i*700 + j;
  return fmaxf(Wrec[idx], 0.f)*Wm[idx]*Ws[idx] + Wf[idx];
}

__global__ void prep_kernel(const float* __restrict__ Wrec, const float* __restrict__ Wm,
                            const float* __restrict__ Ws, const float* __restrict__ Wf,
                            uint4* __restrict__ Wp){
  int s = blockIdx.x*blockDim.x + threadIdx.x;
  if (s >= 12800) return;
  int blk = 0;
  while (s >= tb::qoffs[blk+1]) ++blk;
  int rel = s - tb::qoffs[blk];
  int Q = tb::Qs[blk];
  int half, q, lane;
  if (rel < Q*64){ half = 0; q = rel >> 6; lane = rel & 63; }
  else { int r2 = rel - Q*64; half = 1; q = r2/36; lane = r2 - q*36; }
  int i = tb::tgt[blk] + half*64 + lane;
  unsigned pk[4];
  #pragma unroll
  for (int p = 0; p < 4; ++p){
    int pr = tb::rpb[blk] + q*4 + p;
    float v0 = wval(Wrec,Wm,Ws,Wf, i, 2*pr,   tb::slo[blk], tb::shi[blk]);
    float v1 = wval(Wrec,Wm,Ws,Wf, i, 2*pr+1, tb::slo[blk], tb::shi[blk]);
    pk[p] = pack_f16x2(v0, v1);
  }
  Wp[s] = make_uint4(pk[0], pk[1], pk[2], pk[3]);
}

// ---------------- per-wave config ----------------
namespace cfg {
constexpr int  NL [8] = {64,64,36,36,64,36,64,36};
constexpr int  Q0 [8] = {13,10,13,10,13,13, 7, 7};
constexpr int  Q1 [8] = {13,13,13,13,13,13,13,13};
constexpr int  Q2 [8] = { 7,13, 7,13, 0, 0,13,13};
constexpr int  QO0[8] = {0,2600,832,3240,10200,11032,6900,7348};
constexpr int  QO1[8] = {1300,3600,2132,4432,11500,12332,7600,8432};
constexpr int  QO2[8] = {4900,5600,5348,6432,0,0,8900,9732};
constexpr int  RP0[8] = {0,248,0,248,200,200,0,0};
constexpr int  RP1[8] = {200,300,200,300,248,248,100,100};
constexpr int  RP2[8] = {24,48,24,48,0,0,148,148};
constexpr int  AS0[8] = {0,2,0,2,0,0,0,0};   // 0->acc0, 1->acc1, 2->partial
constexpr int  AS1[8] = {0,2,0,2,0,0,0,0};
constexpr int  AS2[8] = {1,1,1,1,0,0,1,1};
constexpr int  I0 [8] = {0,-1,64,-1,500,564,300,364};  // owned target 0 base (-1: none)
constexpr int  I1 [8] = {100,200,164,264,600,664,400,464}; // owned target 1 base
constexpr bool ITI[8] = {false,false,false,false,true,true,false,false};
constexpr bool PW [8] = {false,true,false,true,false,false,false,false}; // writes str partial
constexpr bool PR [8] = {true,false,true,false,false,false,false,false}; // reads str partial
constexpr int  PB [8] = {0,0,64,64,0,0,0,0};
constexpr bool OUT[8] = {false,false,false,false,true,true,false,false};
constexpr int  OWB[8] = {0,0,0,0,0,64,0,0};
}

template<int Q>
__device__ __forceinline__ float dot_block(const uint4 (&w)[Q],
    const f16* __restrict__ rc, int rpb){
  // 4 independent accumulation chains to hide FMA latency
  float ax = 0.f, ay = 0.f, az = 0.f, aw = 0.f;
  const uint4* rq = (const uint4*)(rc + 2*rpb);
  #pragma unroll
  for (int q = 0; q < Q; ++q){
    uint4 r = rq[q];                 // uniform-address LDS broadcast (b128)
    mac2(w[q].x, r.x, ax);
    mac2(w[q].y, r.y, ay);
    mac2(w[q].z, r.z, az);
    mac2(w[q].w, r.w, aw);
  }
  return (ax + ay) + (az + aw);
}

template<int WID>
__device__ __forceinline__ void wave_loop(const float* __restrict__ inp,
    const float* __restrict__ noise, const float* __restrict__ tonic,
    const float* __restrict__ outw, const uint4* __restrict__ Wp,
    float* __restrict__ out, int b, int lane,
    f16 (*rbuf)[704], float* part_str, float* out_part){
  using namespace cfg;
  constexpr int nl = NL[WID];
  constexpr int q0 = Q0[WID], q1 = Q1[WID], q2 = Q2[WID];
  const bool act = lane < nl;

  // --- load this wave's W slices into registers (once) ---
  uint4 w0[q0], w1[q1], w2[(q2 > 0) ? q2 : 1];
  if (act){
    #pragma unroll
    for (int q = 0; q < q0; ++q) w0[q] = Wp[QO0[WID] + q*nl + lane];
    #pragma unroll
    for (int q = 0; q < q1; ++q) w1[q] = Wp[QO1[WID] + q*nl + lane];
    if constexpr (q2 > 0){
      #pragma unroll
      for (int q = 0; q < q2; ++q) w2[q] = Wp[QO2[WID] + q*nl + lane];
    }
  }
  float ton0 = 0.f, ton1 = 0.f, ow = 0.f;
  if (act){
    if constexpr (I0[WID] >= 0) ton0 = tonic[I0[WID] + lane];
    ton1 = tonic[I1[WID] + lane];
  }
  if constexpr (OUT[WID]) { if (act) ow = outw[OWB[WID] + lane]; }

  float h0 = 0.f, h1 = 0.f;
  for (int t = 0; t < 1000; ++t){
    const f16* rc = rbuf[t & 1];
    f16* rn = rbuf[(t + 1) & 1];
    // issue global loads early (hidden under the matvec)
    const size_t nb = ((size_t)b*1000 + t)*700;
    float n0 = 0.f, n1 = 0.f, x1 = 0.f;
    if (act){
      if constexpr (I0[WID] >= 0) n0 = noise[nb + I0[WID] + lane];
      n1 = noise[nb + I1[WID] + lane];
      if constexpr (ITI[WID])
        x1 = inp[((size_t)b*1000 + t)*100 + (I1[WID] - 600) + lane];
    }
    // ---- phase A: matvec from r_cur ----
    float a0 = 0.f, a1 = 0.f, aP = 0.f;
    if (act){
      { float r = dot_block<q0>(w0, rc, RP0[WID]);
        if constexpr (AS0[WID]==0) a0 += r; else if constexpr (AS0[WID]==1) a1 += r; else aP += r; }
      { float r = dot_block<q1>(w1, rc, RP1[WID]);
        if constexpr (AS1[WID]==0) a0 += r; else if constexpr (AS1[WID]==1) a1 += r; else aP += r; }
      if constexpr (q2 > 0){
        float r = dot_block<q2>(w2, rc, RP2[WID]);
        if constexpr (AS2[WID]==0) a0 += r; else if constexpr (AS2[WID]==1) a1 += r; else aP += r; }
    }
    if constexpr (PW[WID]) { if (act) part_str[PB[WID] + lane] = aP; }
    __syncthreads();   // barrier 1: partials visible; r_cur reads done
    // ---- phase B: h update, write r_next ----
    if (act){
      if constexpr (I0[WID] >= 0){
        float d0 = a0 + ton0;
        if constexpr (PR[WID]) d0 += part_str[PB[WID] + lane];
        h0 = h0 + 0.1f*(-h0 + d0) + 0.01f*n0;
        rn[I0[WID] + lane] = (f16)fmaxf(h0, 0.f);
      }
      {
        float ext = 0.f;
        if constexpr (ITI[WID]) ext = x1 + 0.01f*n1;
        float d1 = a1 + ton1 + ext;
        h1 = h1 + 0.1f*(-h1 + d1) + 0.01f*n1;
        rn[I1[WID] + lane] = (f16)fmaxf(h1, 0.f);
      }
    }
    if constexpr (OUT[WID]){
      float op = act ? fmaxf(h0, 0.f)*ow : 0.f;
      #pragma unroll
      for (int d = 32; d > 0; d >>= 1) op += __shfl_xor(op, d);
      if (lane == 0) out_part[WID - 4] = op;
    }
    __syncthreads();   // barrier 2: r_next + out partials visible
    if constexpr (WID == 0){
      if (lane == 0) out[(size_t)b*1000 + t] = out_part[0] + out_part[1];
    }
  }
}

__global__ __launch_bounds__(512)
__attribute__((amdgpu_waves_per_eu(2, 2)))
void rnn_kernel(const float* __restrict__ inp, const float* __restrict__ noise,
                const float* __restrict__ tonic, const float* __restrict__ outw,
                const uint4* __restrict__ Wp, float* __restrict__ out){
  __shared__ __align__(16) f16 rbuf[2][704];
  __shared__ float part_str[100];
  __shared__ float out_part[2];
  const int tid = threadIdx.x;
  for (int k = tid; k < 704; k += 512){ rbuf[0][k] = (f16)0.f; rbuf[1][k] = (f16)0.f; }
  __syncthreads();
  const int wid = tid >> 6, lane = tid & 63;
  const int b = blockIdx.x;
  switch (wid){
    case 0: wave_loop<0>(inp,noise,tonic,outw,Wp,out,b,lane,rbuf,part_str,out_part); break;
    case 1: wave_loop<1>(inp,noise,tonic,outw,Wp,out,b,lane,rbuf,part_str,out_part); break;
    case 2: wave_loop<2>(inp,noise,tonic,outw,Wp,out,b,lane,rbuf,part_str,out_part); break;
    case 3: wave_loop<3>(inp,noise,tonic,outw,Wp,out,b,lane,rbuf,part_str,out_part); break;
    case 4: wave_loop<4>(inp,noise,tonic,outw,Wp,out,b,lane,rbuf,part_str,out_part); break;
    case 5: wave_loop<5>(inp,noise,tonic,outw,Wp,out,b,lane,rbuf,part_str,out_part); break;
    case 6: wave_loop<6>(inp,noise,tonic,outw,Wp,out,b,lane,rbuf,part_str,out_part); break;
    default: wave_loop<7>(inp,noise,tonic,outw,Wp,out,b,lane,rbuf,part_str,out_part); break;
  }
}

extern "C" void kernel_launch(void* const* d_in, const int* in_sizes, int n_in,
                              void* d_out, int out_size, void* d_ws, size_t ws_size,
                              hipStream_t stream){
  const float* inp   = (const float*)d_in[0];
  const float* noise = (const float*)d_in[1];
  const float* Wrec  = (const float*)d_in[2];
  const float* Wmask = (const float*)d_in[3];
  const float* Wsign = (const float*)d_in[4];
  const float* Wfix  = (const float*)d_in[5];
  const float* tonic = (const float*)d_in[6];
  const float* outw  = (const float*)d_in[7];
  float* out = (float*)d_out;
  uint4* Wp = (uint4*)d_ws;    // 12800 * 16B = 204.8 KB packed weights

  prep_kernel<<<50, 256, 0, stream>>>(Wrec, Wmask, Wsign, Wfix, Wp);
  rnn_kernel<<<128, 512, 0, stream>>>(inp, noise, tonic, outw, Wp, out);
}

// Round 3
// 1555.721 us; speedup vs baseline: 13.1015x; 13.1015x over previous
//
#include <hip/hip_runtime.h>

// mRNN: h_{t+1} = h + 0.1*(-h + relu(h) @ W_eff^T + tonic + ext) + 0.01*noise
// out[b,t] = mean-ish readout over relu(h[500:600]) via out_w
//
// 1 WG per batch (128 WGs, 512 thr = 8 waves). W_eff block-sparse (11 region
// blocks, 12800 f16-pair quads = 204.8KB packed by prep_kernel).
//
// R2 lesson: allocator hard-caps VGPRs at 128/lane regardless of
// __launch_bounds__ second arg or amdgpu_waves_per_eu -> any design needing
// >128 VGPRs spills to scratch catastrophically (WRITE 39MB, FETCH 2.5GB,
// 20ms). So: registers hold <=20 quads/lane (80 VGPR), the remaining 6500
// quads (104KB) live in LDS (copied once at start), streamed per step with
// conflict-free per-lane ds_read_b128. r=relu(h) double-buffered f16 in LDS,
// read as uniform b128 broadcasts. Dot pairs via v_dot2_f32_f16 when available.

typedef _Float16 f16;
typedef _Float16 h2 __attribute__((ext_vector_type(2)));

__device__ __forceinline__ unsigned pack_f16x2(float a, float b){
  union { f16 h[2]; unsigned u; } cv;
  cv.h[0] = (f16)a; cv.h[1] = (f16)b;
  return cv.u;
}

// acc += w.lo*r.lo + w.hi*r.hi  (f16 inputs, f32 accumulate)
__device__ __forceinline__ void mac2(unsigned w, unsigned r, float& acc){
#if __has_builtin(__builtin_amdgcn_fdot2)
  acc = __builtin_amdgcn_fdot2(__builtin_bit_cast(h2, w), __builtin_bit_cast(h2, r), acc, false);
#else
  union U { unsigned u; h2 v; } cw, cr;
  cw.u = w; cr.u = r;
  acc += (float)cw.v.x * (float)cr.v.x;
  acc += (float)cw.v.y * (float)cr.v.y;
#endif
}

// ---------------- block tables (prep) ----------------
namespace tb {
constexpr int qoffs[12] = {0,1300,2600,3600,4900,5600,6900,7600,8900,10200,11500,12800};
constexpr int Qs [11] = {13,13,10,13, 7,13, 7,13,13,13,13};
constexpr int tgt[11] = {0,0,0,0,100,200,300,300,400,500,500};
constexpr int slo[11] = {0,400,500,600, 50,100,  0,200,300,400,500};
constexpr int shi[11] = {100,500,570,700,100,200, 50,300,400,500,600};
constexpr int rpb[11] = {0,200,248,300, 24, 48,  0,100,148,200,248};
}

__device__ __forceinline__ float wval(const float* __restrict__ Wrec,
    const float* __restrict__ Wm, const float* __restrict__ Ws,
    const float* __restrict__ Wf, int i, int j, int lo, int hi){
  if (j < lo || j >= hi) return 0.f;
  int idx = i*700 + j;
  return fmaxf(Wrec[idx], 0.f)*Wm[idx]*Ws[idx] + Wf[idx];
}

__global__ void prep_kernel(const float* __restrict__ Wrec, const float* __restrict__ Wm,
                            const float* __restrict__ Ws, const float* __restrict__ Wf,
                            uint4* __restrict__ Wp){
  int s = blockIdx.x*blockDim.x + threadIdx.x;
  if (s >= 12800) return;
  int blk = 0;
  while (s >= tb::qoffs[blk+1]) ++blk;
  int rel = s - tb::qoffs[blk];
  int Q = tb::Qs[blk];
  int half, q, lane;
  if (rel < Q*64){ half = 0; q = rel >> 6; lane = rel & 63; }
  else { int r2 = rel - Q*64; half = 1; q = r2/36; lane = r2 - q*36; }
  int i = tb::tgt[blk] + half*64 + lane;
  unsigned pk[4];
  #pragma unroll
  for (int p = 0; p < 4; ++p){
    int pr = tb::rpb[blk] + q*4 + p;
    float v0 = wval(Wrec,Wm,Ws,Wf, i, 2*pr,   tb::slo[blk], tb::shi[blk]);
    float v1 = wval(Wrec,Wm,Ws,Wf, i, 2*pr+1, tb::slo[blk], tb::shi[blk]);
    pk[p] = pack_f16x2(v0, v1);
  }
  Wp[s] = make_uint4(pk[0], pk[1], pk[2], pk[3]);
}

// ---------------- per-wave config ----------------
// Register blocks A,B (<=20 quads total = 80 VGPR); streamed blocks S1,S2 in LDS.
namespace cfg {
constexpr int  NL  [8] = {64,64,36,36,64,36,64,36};
// register block A
constexpr int  QA  [8] = {13,10,13,10,13,13, 7, 7};
constexpr int  QAO [8] = {0,2600,832,3240,10200,11032,6900,7348};
constexpr int  RPA [8] = {0,248,0,248,200,200,0,0};
constexpr int  ASA [8] = {0,2,0,2,0,0,0,0};          // 0->acc0, 1->acc1, 2->partial
// register block B (0 = none)
constexpr int  QB  [8] = {7,0,7,0,0,0,13,13};
constexpr int  QBO [8] = {4900,0,5348,0,0,0,7600,8432};
constexpr int  RPB [8] = {24,0,24,0,0,0,100,100};
constexpr int  ASB [8] = {1,0,1,0,0,0,0,0};
// streamed block S1 (LDS quad base)
constexpr int  QS1 [8] = {13,13,13,13,13,13,13,13};
constexpr int  SB1 [8] = {0,832,2496,2964,3900,4732,5200,6032};
constexpr int  RPS1[8] = {200,48,200,48,248,248,148,148};
constexpr int  ASS1[8] = {0,1,0,1,0,0,1,1};
// streamed block S2 (0 = none)
constexpr int  QS2 [8] = {0,13,0,13,0,0,0,0};
constexpr int  SB2 [8] = {0,1664,0,3432,0,0,0,0};
constexpr int  RPS2[8] = {0,300,0,300,0,0,0,0};
constexpr int  ASS2[8] = {0,2,0,2,0,0,0,0};
// targets / roles (unchanged from verified R0 kernel)
constexpr int  I0 [8] = {0,-1,64,-1,500,564,300,364};
constexpr int  I1 [8] = {100,200,164,264,600,664,400,464};
constexpr bool ITI[8] = {false,false,false,false,true,true,false,false};
constexpr bool PW [8] = {false,true,false,true,false,false,false,false};
constexpr bool PR [8] = {true,false,true,false,false,false,false,false};
constexpr int  PB [8] = {0,0,64,64,0,0,0,0};
constexpr bool OUT[8] = {false,false,false,false,true,true,false,false};
constexpr int  OWB[8] = {0,0,0,0,0,64,0,0};
}

// startup LDS fill: contiguous slices of Wp, layout preserved (q*nl + lane)
namespace seg {
constexpr int N = 10;
constexpr int src[N] = {1300,5600,3600,2132,6432,4432,11500,12332,8900,9732};
constexpr int dst[N] = {0,832,1664,2496,2964,3432,3900,4732,5200,6032};
constexpr int cnt[N] = {832,832,832,468,468,468,832,468,832,468};
constexpr int TOTAL = 6500;   // 104 KB
}

template<int Q>
__device__ __forceinline__ float dot_reg(const uint4 (&w)[Q], const f16* rc, int rpb){
  float ax = 0.f, ay = 0.f, az = 0.f, aw = 0.f;
  const uint4* rq = (const uint4*)(rc + 2*rpb);
  #pragma unroll
  for (int q = 0; q < Q; ++q){
    uint4 r = rq[q];                 // uniform-address LDS broadcast (b128)
    mac2(w[q].x, r.x, ax);
    mac2(w[q].y, r.y, ay);
    mac2(w[q].z, r.z, az);
    mac2(w[q].w, r.w, aw);
  }
  return (ax + ay) + (az + aw);
}

template<int Q, int NLANE>
__device__ __forceinline__ float dot_lds(const uint4* swq, int lane, const f16* rc, int rpb){
  float ax = 0.f, ay = 0.f, az = 0.f, aw = 0.f;
  const uint4* rq = (const uint4*)(rc + 2*rpb);
  #pragma unroll
  for (int q = 0; q < Q; ++q){
    uint4 w = swq[q*NLANE + lane];   // per-lane contiguous b128, conflict-free
    uint4 r = rq[q];
    mac2(w.x, r.x, ax);
    mac2(w.y, r.y, ay);
    mac2(w.z, r.z, az);
    mac2(w.w, r.w, aw);
  }
  return (ax + ay) + (az + aw);
}

template<int WID>
__device__ __forceinline__ void wave_loop(const float* __restrict__ inp,
    const float* __restrict__ noise, const float* __restrict__ tonic,
    const float* __restrict__ outw, const uint4* __restrict__ Wp,
    float* __restrict__ out, int b, int lane,
    f16 (*rbuf)[704], const uint4* swq, float* part_str, float* out_part){
  using namespace cfg;
  constexpr int nl = NL[WID];
  constexpr int qa = QA[WID], qb = QB[WID], qs1 = QS1[WID], qs2 = QS2[WID];
  const bool act = lane < nl;

  // register-resident W (<=20 quads = 80 VGPR)
  uint4 wa[qa], wb[(qb > 0) ? qb : 1];
  if (act){
    #pragma unroll
    for (int q = 0; q < qa; ++q) wa[q] = Wp[QAO[WID] + q*nl + lane];
    if constexpr (qb > 0){
      #pragma unroll
      for (int q = 0; q < qb; ++q) wb[q] = Wp[QBO[WID] + q*nl + lane];
    }
  }
  float ton0 = 0.f, ton1 = 0.f, ow = 0.f;
  if (act){
    if constexpr (I0[WID] >= 0) ton0 = tonic[I0[WID] + lane];
    ton1 = tonic[I1[WID] + lane];
  }
  if constexpr (OUT[WID]) { if (act) ow = outw[OWB[WID] + lane]; }

  float h0 = 0.f, h1 = 0.f;
  for (int t = 0; t < 1000; ++t){
    const f16* rc = rbuf[t & 1];
    f16* rn = rbuf[(t + 1) & 1];
    const size_t nb = ((size_t)b*1000 + t)*700;
    float n0 = 0.f, n1 = 0.f, x1 = 0.f;
    if (act){
      if constexpr (I0[WID] >= 0) n0 = noise[nb + I0[WID] + lane];
      n1 = noise[nb + I1[WID] + lane];
      if constexpr (ITI[WID])
        x1 = inp[((size_t)b*1000 + t)*100 + (I1[WID] - 600) + lane];
    }
    // ---- phase A: matvec from r_cur ----
    float a0 = 0.f, a1 = 0.f, aP = 0.f;
    if (act){
      { float r = dot_reg<qa>(wa, rc, RPA[WID]);
        if constexpr (ASA[WID]==0) a0 += r; else if constexpr (ASA[WID]==1) a1 += r; else aP += r; }
      if constexpr (qb > 0){
        float r = dot_reg<qb>(wb, rc, RPB[WID]);
        if constexpr (ASB[WID]==0) a0 += r; else if constexpr (ASB[WID]==1) a1 += r; else aP += r; }
      { float r = dot_lds<qs1, nl>(swq + SB1[WID], lane, rc, RPS1[WID]);
        if constexpr (ASS1[WID]==0) a0 += r; else if constexpr (ASS1[WID]==1) a1 += r; else aP += r; }
      if constexpr (qs2 > 0){
        float r = dot_lds<qs2, nl>(swq + SB2[WID], lane, rc, RPS2[WID]);
        if constexpr (ASS2[WID]==0) a0 += r; else if constexpr (ASS2[WID]==1) a1 += r; else aP += r; }
    }
    if constexpr (PW[WID]) { if (act) part_str[PB[WID] + lane] = aP; }
    __syncthreads();   // barrier 1: partials visible; r_cur reads done
    // ---- phase B: h update, write r_next ----
    if (act){
      if constexpr (I0[WID] >= 0){
        float d0 = a0 + ton0;
        if constexpr (PR[WID]) d0 += part_str[PB[WID] + lane];
        h0 = h0 + 0.1f*(-h0 + d0) + 0.01f*n0;
        rn[I0[WID] + lane] = (f16)fmaxf(h0, 0.f);
      }
      {
        float ext = 0.f;
        if constexpr (ITI[WID]) ext = x1 + 0.01f*n1;
        float d1 = a1 + ton1 + ext;
        h1 = h1 + 0.1f*(-h1 + d1) + 0.01f*n1;
        rn[I1[WID] + lane] = (f16)fmaxf(h1, 0.f);
      }
    }
    if constexpr (OUT[WID]){
      float op = act ? fmaxf(h0, 0.f)*ow : 0.f;
      #pragma unroll
      for (int d = 32; d > 0; d >>= 1) op += __shfl_xor(op, d);
      if (lane == 0) out_part[WID - 4] = op;
    }
    __syncthreads();   // barrier 2: r_next + out partials visible
    if constexpr (WID == 0){
      if (lane == 0) out[(size_t)b*1000 + t] = out_part[0] + out_part[1];
    }
  }
}

__global__ __launch_bounds__(512)
void rnn_kernel(const float* __restrict__ inp, const float* __restrict__ noise,
                const float* __restrict__ tonic, const float* __restrict__ outw,
                const uint4* __restrict__ Wp, float* __restrict__ out){
  __shared__ __align__(16) uint4 swq[seg::TOTAL];   // 104 KB streamed W
  __shared__ __align__(16) f16 rbuf[2][704];
  __shared__ float part_str[100];
  __shared__ float out_part[2];
  const int tid = threadIdx.x;
  // one-time fill of LDS-resident W (straight slice copies, layout preserved)
  #pragma unroll
  for (int s = 0; s < seg::N; ++s)
    for (int k = tid; k < seg::cnt[s]; k += 512)
      swq[seg::dst[s] + k] = Wp[seg::src[s] + k];
  for (int k = tid; k < 704; k += 512){ rbuf[0][k] = (f16)0.f; rbuf[1][k] = (f16)0.f; }
  __syncthreads();
  const int wid = tid >> 6, lane = tid & 63;
  const int b = blockIdx.x;
  switch (wid){
    case 0: wave_loop<0>(inp,noise,tonic,outw,Wp,out,b,lane,rbuf,swq,part_str,out_part); break;
    case 1: wave_loop<1>(inp,noise,tonic,outw,Wp,out,b,lane,rbuf,swq,part_str,out_part); break;
    case 2: wave_loop<2>(inp,noise,tonic,outw,Wp,out,b,lane,rbuf,swq,part_str,out_part); break;
    case 3: wave_loop<3>(inp,noise,tonic,outw,Wp,out,b,lane,rbuf,swq,part_str,out_part); break;
    case 4: wave_loop<4>(inp,noise,tonic,outw,Wp,out,b,lane,rbuf,swq,part_str,out_part); break;
    case 5: wave_loop<5>(inp,noise,tonic,outw,Wp,out,b,lane,rbuf,swq,part_str,out_part); break;
    case 6: wave_loop<6>(inp,noise,tonic,outw,Wp,out,b,lane,rbuf,swq,part_str,out_part); break;
    default: wave_loop<7>(inp,noise,tonic,outw,Wp,out,b,lane,rbuf,swq,part_str,out_part); break;
  }
}

extern "C" void kernel_launch(void* const* d_in, const int* in_sizes, int n_in,
                              void* d_out, int out_size, void* d_ws, size_t ws_size,
                              hipStream_t stream){
  const float* inp   = (const float*)d_in[0];
  const float* noise = (const float*)d_in[1];
  const float* Wrec  = (const float*)d_in[2];
  const float* Wmask = (const float*)d_in[3];
  const float* Wsign = (const float*)d_in[4];
  const float* Wfix  = (const float*)d_in[5];
  const float* tonic = (const float*)d_in[6];
  const float* outw  = (const float*)d_in[7];
  float* out = (float*)d_out;
  uint4* Wp = (uint4*)d_ws;    // 12800 * 16B = 204.8 KB packed weights

  prep_kernel<<<50, 256, 0, stream>>>(Wrec, Wmask, Wsign, Wfix, Wp);
  rnn_kernel<<<128, 512, 0, stream>>>(inp, noise, tonic, outw, Wp, out);
}

// Round 4
// 1540.371 us; speedup vs baseline: 13.2321x; 1.0100x over previous
//
#include <hip/hip_runtime.h>

// mRNN: h_{t+1} = h + 0.1*(-h + relu(h) @ W_eff^T + tonic + ext) + 0.01*noise
// out[b,t] = readout over relu(h[500:600]) via out_w
//
// 1 WG per batch (128 WGs, 512 thr = 8 waves). W_eff block-sparse (11 region
// blocks, 12800 f16-pair quads = 204.8KB packed by prep_kernel into d_ws).
//
// R2 lesson: allocator hard-caps VGPRs at 128/lane -> reg W <= 20 quads/lane.
// R3 result: 1555us, LDS-pipe-bound (256 r-broadcasts + 130 wave-wide W
//   streams + writes ~ 2.6-3k cy/step on the single LDS pipe).
// R4 change: stream the non-register W from GLOBAL (L2-resident, shared by
//   all WGs) instead of LDS -> W streams move to the VMEM pipe; LDS pipe
//   carries only r-broadcasts. Also extend every wave to the full 20-quad
//   register budget (reg-cached prefix of its streamed segment): streamed
//   instrs 130 -> 96.

typedef _Float16 f16;
typedef _Float16 h2 __attribute__((ext_vector_type(2)));

__device__ __forceinline__ unsigned pack_f16x2(float a, float b){
  union { f16 h[2]; unsigned u; } cv;
  cv.h[0] = (f16)a; cv.h[1] = (f16)b;
  return cv.u;
}

// acc += w.lo*r.lo + w.hi*r.hi  (f16 inputs, f32 accumulate)
__device__ __forceinline__ void mac2(unsigned w, unsigned r, float& acc){
#if __has_builtin(__builtin_amdgcn_fdot2)
  acc = __builtin_amdgcn_fdot2(__builtin_bit_cast(h2, w), __builtin_bit_cast(h2, r), acc, false);
#else
  union U { unsigned u; h2 v; } cw, cr;
  cw.u = w; cr.u = r;
  acc += (float)cw.v.x * (float)cr.v.x;
  acc += (float)cw.v.y * (float)cr.v.y;
#endif
}

// ---------------- block tables (prep) ----------------
namespace tb {
constexpr int qoffs[12] = {0,1300,2600,3600,4900,5600,6900,7600,8900,10200,11500,12800};
constexpr int Qs [11] = {13,13,10,13, 7,13, 7,13,13,13,13};
constexpr int tgt[11] = {0,0,0,0,100,200,300,300,400,500,500};
constexpr int slo[11] = {0,400,500,600, 50,100,  0,200,300,400,500};
constexpr int shi[11] = {100,500,570,700,100,200, 50,300,400,500,600};
constexpr int rpb[11] = {0,200,248,300, 24, 48,  0,100,148,200,248};
}

__device__ __forceinline__ float wval(const float* __restrict__ Wrec,
    const float* __restrict__ Wm, const float* __restrict__ Ws,
    const float* __restrict__ Wf, int i, int j, int lo, int hi){
  if (j < lo || j >= hi) return 0.f;
  int idx = i*700 + j;
  return fmaxf(Wrec[idx], 0.f)*Wm[idx]*Ws[idx] + Wf[idx];
}

__global__ void prep_kernel(const float* __restrict__ Wrec, const float* __restrict__ Wm,
                            const float* __restrict__ Ws, const float* __restrict__ Wf,
                            uint4* __restrict__ Wp){
  int s = blockIdx.x*blockDim.x + threadIdx.x;
  if (s >= 12800) return;
  int blk = 0;
  while (s >= tb::qoffs[blk+1]) ++blk;
  int rel = s - tb::qoffs[blk];
  int Q = tb::Qs[blk];
  int half, q, lane;
  if (rel < Q*64){ half = 0; q = rel >> 6; lane = rel & 63; }
  else { int r2 = rel - Q*64; half = 1; q = r2/36; lane = r2 - q*36; }
  int i = tb::tgt[blk] + half*64 + lane;
  unsigned pk[4];
  #pragma unroll
  for (int p = 0; p < 4; ++p){
    int pr = tb::rpb[blk] + q*4 + p;
    float v0 = wval(Wrec,Wm,Ws,Wf, i, 2*pr,   tb::slo[blk], tb::shi[blk]);
    float v1 = wval(Wrec,Wm,Ws,Wf, i, 2*pr+1, tb::slo[blk], tb::shi[blk]);
    pk[p] = pack_f16x2(v0, v1);
  }
  Wp[s] = make_uint4(pk[0], pk[1], pk[2], pk[3]);
}

// ---------------- per-wave config ----------------
// Register segments A,B,C (<=20 quads = 80 VGPR); streamed segments S1,S2
// read from GLOBAL (L2-resident Wp) each step.
namespace cfg {
constexpr int  NL  [8] = {64,64,36,36,64,36,64,36};
// register segment A
constexpr int  QA  [8] = {13,10,13,10,13,13, 7, 7};
constexpr int  QAO [8] = {0,2600,832,3240,10200,11032,6900,7348};
constexpr int  RPA [8] = {0,248,0,248,200,200,0,0};
constexpr int  ASA [8] = {0,2,0,2,0,0,0,0};          // 0->acc0, 1->acc1, 2->partial
// register segment B (0 = none)
constexpr int  QB  [8] = {7,0,7,0,0,0,13,13};
constexpr int  QBO [8] = {4900,0,5348,0,0,0,7600,8432};
constexpr int  RPB [8] = {24,0,24,0,0,0,100,100};
constexpr int  ASB [8] = {1,0,1,0,0,0,0,0};
// register segment C: reg-cached prefix of the streamed block (0 = none)
constexpr int  QC  [8] = {0,10,0,10,7,7,0,0};
constexpr int  GC  [8] = {1300,5600,2132,6432,11500,12332,8900,9732};
constexpr int  RPC [8] = {200,48,200,48,248,248,148,148};
constexpr int  ASC [8] = {0,1,0,1,0,0,1,1};
// streamed segment S1 (global quad base, remainder after C)
constexpr int  QS1 [8] = {13,3,13,3,6,6,13,13};
constexpr int  GS1 [8] = {1300,6240,2132,6792,11948,12584,8900,9732};
constexpr int  RPS1[8] = {200,88,200,88,276,276,148,148};
constexpr int  ASS1[8] = {0,1,0,1,0,0,1,1};
// streamed segment S2 (0 = none)
constexpr int  QS2 [8] = {0,13,0,13,0,0,0,0};
constexpr int  GS2 [8] = {0,3600,0,4432,0,0,0,0};
constexpr int  RPS2[8] = {0,300,0,300,0,0,0,0};
constexpr int  ASS2[8] = {0,2,0,2,0,0,0,0};
// targets / roles (unchanged from verified R0 kernel)
constexpr int  I0 [8] = {0,-1,64,-1,500,564,300,364};
constexpr int  I1 [8] = {100,200,164,264,600,664,400,464};
constexpr bool ITI[8] = {false,false,false,false,true,true,false,false};
constexpr bool PW [8] = {false,true,false,true,false,false,false,false};
constexpr bool PR [8] = {true,false,true,false,false,false,false,false};
constexpr int  PB [8] = {0,0,64,64,0,0,0,0};
constexpr bool OUT[8] = {false,false,false,false,true,true,false,false};
constexpr int  OWB[8] = {0,0,0,0,0,64,0,0};
}

template<int Q>
__device__ __forceinline__ float dot_reg(const uint4 (&w)[Q], const f16* rc, int rpb){
  float ax = 0.f, ay = 0.f, az = 0.f, aw = 0.f;
  const uint4* rq = (const uint4*)(rc + 2*rpb);
  #pragma unroll
  for (int q = 0; q < Q; ++q){
    uint4 r = rq[q];                 // uniform-address LDS broadcast (b128)
    mac2(w[q].x, r.x, ax);
    mac2(w[q].y, r.y, ay);
    mac2(w[q].z, r.z, az);
    mac2(w[q].w, r.w, aw);
  }
  return (ax + ay) + (az + aw);
}

template<int Q, int NLANE>
__device__ __forceinline__ float dot_glb(const uint4* __restrict__ wg, int lane,
                                         const f16* rc, int rpb){
  float ax = 0.f, ay = 0.f, az = 0.f, aw = 0.f;
  const uint4* rq = (const uint4*)(rc + 2*rpb);
  #pragma unroll
  for (int q = 0; q < Q; ++q){
    uint4 w = wg[q*NLANE + lane];    // L2-resident global load (VMEM pipe)
    uint4 r = rq[q];
    mac2(w.x, r.x, ax);
    mac2(w.y, r.y, ay);
    mac2(w.z, r.z, az);
    mac2(w.w, r.w, aw);
  }
  return (ax + ay) + (az + aw);
}

template<int WID>
__device__ __forceinline__ void wave_loop(const float* __restrict__ inp,
    const float* __restrict__ noise, const float* __restrict__ tonic,
    const float* __restrict__ outw, const uint4* __restrict__ Wp,
    float* __restrict__ out, int b, int lane,
    f16 (*rbuf)[704], float* part_str, float* out_part){
  using namespace cfg;
  constexpr int nl = NL[WID];
  constexpr int qa = QA[WID], qb = QB[WID], qc = QC[WID];
  constexpr int qs1 = QS1[WID], qs2 = QS2[WID];
  const bool act = lane < nl;

  // register-resident W (<=20 quads = 80 VGPR)
  uint4 wa[qa], wb[(qb > 0) ? qb : 1], wc[(qc > 0) ? qc : 1];
  if (act){
    #pragma unroll
    for (int q = 0; q < qa; ++q) wa[q] = Wp[QAO[WID] + q*nl + lane];
    if constexpr (qb > 0){
      #pragma unroll
      for (int q = 0; q < qb; ++q) wb[q] = Wp[QBO[WID] + q*nl + lane];
    }
    if constexpr (qc > 0){
      #pragma unroll
      for (int q = 0; q < qc; ++q) wc[q] = Wp[GC[WID] + q*nl + lane];
    }
  }
  float ton0 = 0.f, ton1 = 0.f, ow = 0.f;
  if (act){
    if constexpr (I0[WID] >= 0) ton0 = tonic[I0[WID] + lane];
    ton1 = tonic[I1[WID] + lane];
  }
  if constexpr (OUT[WID]) { if (act) ow = outw[OWB[WID] + lane]; }

  float h0 = 0.f, h1 = 0.f;
  for (int t = 0; t < 1000; ++t){
    const f16* rc = rbuf[t & 1];
    f16* rn = rbuf[(t + 1) & 1];
    const size_t nb = ((size_t)b*1000 + t)*700;
    float n0 = 0.f, n1 = 0.f, x1 = 0.f;
    if (act){
      if constexpr (I0[WID] >= 0) n0 = noise[nb + I0[WID] + lane];
      n1 = noise[nb + I1[WID] + lane];
      if constexpr (ITI[WID])
        x1 = inp[((size_t)b*1000 + t)*100 + (I1[WID] - 600) + lane];
    }
    // ---- phase A: matvec from r_cur ----
    float a0 = 0.f, a1 = 0.f, aP = 0.f;
    if (act){
      { float r = dot_reg<qa>(wa, rc, RPA[WID]);
        if constexpr (ASA[WID]==0) a0 += r; else if constexpr (ASA[WID]==1) a1 += r; else aP += r; }
      if constexpr (qb > 0){
        float r = dot_reg<qb>(wb, rc, RPB[WID]);
        if constexpr (ASB[WID]==0) a0 += r; else if constexpr (ASB[WID]==1) a1 += r; else aP += r; }
      if constexpr (qc > 0){
        float r = dot_reg<qc>(wc, rc, RPC[WID]);
        if constexpr (ASC[WID]==0) a0 += r; else if constexpr (ASC[WID]==1) a1 += r; else aP += r; }
      { float r = dot_glb<qs1, nl>(Wp + GS1[WID], lane, rc, RPS1[WID]);
        if constexpr (ASS1[WID]==0) a0 += r; else if constexpr (ASS1[WID]==1) a1 += r; else aP += r; }
      if constexpr (qs2 > 0){
        float r = dot_glb<qs2, nl>(Wp + GS2[WID], lane, rc, RPS2[WID]);
        if constexpr (ASS2[WID]==0) a0 += r; else if constexpr (ASS2[WID]==1) a1 += r; else aP += r; }
    }
    if constexpr (PW[WID]) { if (act) part_str[PB[WID] + lane] = aP; }
    __syncthreads();   // barrier 1: partials visible; r_cur reads done
    // ---- phase B: h update, write r_next ----
    if (act){
      if constexpr (I0[WID] >= 0){
        float d0 = a0 + ton0;
        if constexpr (PR[WID]) d0 += part_str[PB[WID] + lane];
        h0 = h0 + 0.1f*(-h0 + d0) + 0.01f*n0;
        rn[I0[WID] + lane] = (f16)fmaxf(h0, 0.f);
      }
      {
        float ext = 0.f;
        if constexpr (ITI[WID]) ext = x1 + 0.01f*n1;
        float d1 = a1 + ton1 + ext;
        h1 = h1 + 0.1f*(-h1 + d1) + 0.01f*n1;
        rn[I1[WID] + lane] = (f16)fmaxf(h1, 0.f);
      }
    }
    if constexpr (OUT[WID]){
      float op = act ? fmaxf(h0, 0.f)*ow : 0.f;
      #pragma unroll
      for (int d = 32; d > 0; d >>= 1) op += __shfl_xor(op, d);
      if (lane == 0) out_part[WID - 4] = op;
    }
    __syncthreads();   // barrier 2: r_next + out partials visible
    if constexpr (WID == 0){
      if (lane == 0) out[(size_t)b*1000 + t] = out_part[0] + out_part[1];
    }
  }
}

__global__ __launch_bounds__(512)
void rnn_kernel(const float* __restrict__ inp, const float* __restrict__ noise,
                const float* __restrict__ tonic, const float* __restrict__ outw,
                const uint4* __restrict__ Wp, float* __restrict__ out){
  __shared__ __align__(16) f16 rbuf[2][704];
  __shared__ float part_str[100];
  __shared__ float out_part[2];
  const int tid = threadIdx.x;
  for (int k = tid; k < 704; k += 512){ rbuf[0][k] = (f16)0.f; rbuf[1][k] = (f16)0.f; }
  __syncthreads();
  const int wid = tid >> 6, lane = tid & 63;
  const int b = blockIdx.x;
  switch (wid){
    case 0: wave_loop<0>(inp,noise,tonic,outw,Wp,out,b,lane,rbuf,part_str,out_part); break;
    case 1: wave_loop<1>(inp,noise,tonic,outw,Wp,out,b,lane,rbuf,part_str,out_part); break;
    case 2: wave_loop<2>(inp,noise,tonic,outw,Wp,out,b,lane,rbuf,part_str,out_part); break;
    case 3: wave_loop<3>(inp,noise,tonic,outw,Wp,out,b,lane,rbuf,part_str,out_part); break;
    case 4: wave_loop<4>(inp,noise,tonic,outw,Wp,out,b,lane,rbuf,part_str,out_part); break;
    case 5: wave_loop<5>(inp,noise,tonic,outw,Wp,out,b,lane,rbuf,part_str,out_part); break;
    case 6: wave_loop<6>(inp,noise,tonic,outw,Wp,out,b,lane,rbuf,part_str,out_part); break;
    default: wave_loop<7>(inp,noise,tonic,outw,Wp,out,b,lane,rbuf,part_str,out_part); break;
  }
}

extern "C" void kernel_launch(void* const* d_in, const int* in_sizes, int n_in,
                              void* d_out, int out_size, void* d_ws, size_t ws_size,
                              hipStream_t stream){
  const float* inp   = (const float*)d_in[0];
  const float* noise = (const float*)d_in[1];
  const float* Wrec  = (const float*)d_in[2];
  const float* Wmask = (const float*)d_in[3];
  const float* Wsign = (const float*)d_in[4];
  const float* Wfix  = (const float*)d_in[5];
  const float* tonic = (const float*)d_in[6];
  const float* outw  = (const float*)d_in[7];
  float* out = (float*)d_out;
  uint4* Wp = (uint4*)d_ws;    // 12800 * 16B = 204.8 KB packed weights

  prep_kernel<<<50, 256, 0, stream>>>(Wrec, Wmask, Wsign, Wfix, Wp);
  rnn_kernel<<<128, 512, 0, stream>>>(inp, noise, tonic, outw, Wp, out);
}